// Round 16
// baseline (84.538 us; speedup 1.0000x reference)
//
#include <hip/hip_runtime.h>
#include <math.h>

// Problem constants
#define B_ 4
#define C_ 128
#define L_ 4096       // H*W
#define EPS_ 1e-5f

typedef __attribute__((ext_vector_type(8))) short short8;   // 8 x bf16 MFMA A/B frag (4 VGPRs)
typedef __attribute__((ext_vector_type(4))) float f32x4;
typedef __attribute__((ext_vector_type(16))) float f32x16;  // 32x32 MFMA C/D frag

static __device__ __forceinline__ unsigned short f2bf(float f) {
  union { float f; unsigned u; } v; v.f = f;
  return (unsigned short)((v.u + 0x7FFFu + ((v.u >> 16) & 1u)) >> 16);  // RNE
}
static __device__ __forceinline__ f32x4 fzero() {
  f32x4 z; z[0] = 0.f; z[1] = 0.f; z[2] = 0.f; z[3] = 0.f; return z;
}
static __device__ __forceinline__ f32x16 zero16() {
  f32x16 z;
#pragma unroll
  for (int i = 0; i < 16; ++i) z[i] = 0.f;
  return z;
}
static __device__ __forceinline__ float fexp2(float x) {
  return __builtin_amdgcn_exp2f(x);   // v_exp_f32
}
static __device__ __forceinline__ unsigned cvtpk(float lo, float hi) {
  unsigned r;
  asm("v_cvt_pk_bf16_f32 %0, %1, %2" : "=v"(r) : "v"(lo), "v"(hi));
  return r;
}
#define PLSWAP(a, b) asm("v_permlane32_swap_b32 %0, %1" : "+v"(a), "+v"(b))

// Frag-major K/V layout (written by qkv_gemm, read by attn_g):
//   byte addr = bh*262144 + s*2048 + blk*1024 + lane*16 + j*2
//   lane = hi*32 + lq  (lq = l&31, hi = l>>5)
//   K element: K[32s + lq][blk*16 + hi*8 + j]      (kpos-major rows)
//   V element: V^T[lq][32s + blk*16 + hi*8 + j]    (d-major rows)
// => every attention frag load is 64 lanes x 16B fully contiguous (1KB).

// ---------------------------------------------------------------------------
// K0: GroupNorm stats (blocks 0..127) + weight prep (blocks 128..385) merged.
// ---------------------------------------------------------------------------
__global__ __launch_bounds__(256) void gn_prep(const float* __restrict__ x,
                                               float* __restrict__ mean,
                                               float* __restrict__ rstd,
                                               const float* __restrict__ wqkv,
                                               const float* __restrict__ bqkv,
                                               const float* __restrict__ wproj,
                                               unsigned short* __restrict__ wqkv_bf,
                                               unsigned short* __restrict__ wproj_bf,
                                               float* __restrict__ bqkv_s) {
  int bx = blockIdx.x;
  int tid = threadIdx.x;
  if (bx < 128) {
    int g = bx & 31, b = bx >> 5;
    const f32x4* p4 = (const f32x4*)(x + (size_t)(b * C_ + g * 4) * L_);
    float s = 0.f, sq = 0.f;
#pragma unroll
    for (int i = 0; i < 16; ++i) {
      f32x4 v = p4[tid + i * 256];
      s += v[0] + v[1] + v[2] + v[3];
      sq += v[0]*v[0] + v[1]*v[1] + v[2]*v[2] + v[3]*v[3];
    }
#pragma unroll
    for (int m = 1; m < 64; m <<= 1) { s += __shfl_xor(s, m, 64); sq += __shfl_xor(sq, m, 64); }
    __shared__ float ls[8];
    int w = tid >> 6;
    if ((tid & 63) == 0) { ls[w] = s; ls[4 + w] = sq; }
    __syncthreads();
    if (tid == 0) {
      float S = ls[0] + ls[1] + ls[2] + ls[3];
      float Q = ls[4] + ls[5] + ls[6] + ls[7];
      float mu = S * (1.f / 16384.f);
      float var = Q * (1.f / 16384.f) - mu * mu;
      mean[b * 32 + g] = mu;
      rstd[b * 32 + g] = rsqrtf(var + EPS_);
    }
  } else {
    const float SC = 0.42044820762685725f * 1.2011224087864498f;  // scale*sqrt(log2e)
    int i = (bx - 128) * 256 + tid;
    if (i < 49152) {
      int o = i >> 7;
      wqkv_bf[i] = f2bf(wqkv[i] * (o < 256 ? SC : 1.f));
    } else if (i < 65536) {
      wproj_bf[i - 49152] = f2bf(wproj[i - 49152]);
    } else if (i < 65920) {
      int o = i - 65536;
      bqkv_s[o] = bqkv[o] * (o < 256 ? SC : 1.f);
    }
  }
}

// ---------------------------------------------------------------------------
// K2: fused GroupNorm-normalize + QKV 1x1 conv (r9-exact, 64-pos tiles).
// Emits q as [bh][pos][32], k/v frag-major.
// ---------------------------------------------------------------------------
__global__ __launch_bounds__(256) void qkv_gemm(const float* __restrict__ x,
                                                const float* __restrict__ gamma,
                                                const float* __restrict__ beta,
                                                const float* __restrict__ mean,
                                                const float* __restrict__ rstd,
                                                const unsigned short* __restrict__ wqkv_bf,
                                                const float* __restrict__ bqkv_s,
                                                unsigned short* __restrict__ qbuf,
                                                char* __restrict__ kf,
                                                char* __restrict__ vf) {
  __shared__ char lds[64 * 256];  // [pos][c] bf16, rows 256B, XOR-swizzled
  int b = blockIdx.y;
  int pos0 = blockIdx.x * 64;
  int tid = threadIdx.x;

#pragma unroll
  for (int it = 0; it < 4; ++it) {
    int pi = it * 256 + tid;         // 0..1023 (c-pair, 4-pos unit)
    int c = (pi >> 4) * 2;           // even c
    int pl = (pi & 15) * 4;
    const float* xc = x + (size_t)(b * C_ + c) * L_ + pos0 + pl;
    f32x4 v0 = *(const f32x4*)xc;
    f32x4 v1 = *(const f32x4*)(xc + L_);
    int g = c >> 2;                  // c,c+1 always share a group (c even)
    float rs = rstd[b * 32 + g], mu = mean[b * 32 + g];
    float A0 = rs * gamma[c],     B0 = beta[c]     - mu * A0;
    float A1 = rs * gamma[c + 1], B1 = beta[c + 1] - mu * A1;
#pragma unroll
    for (int i = 0; i < 4; ++i) {
      int row = pl + i;
      unsigned u = cvtpk(v0[i] * A0 + B0, v1[i] * A1 + B1);
      *(unsigned*)(lds + row * 256 + ((c * 2) ^ ((row & 7) << 4))) = u;
    }
  }
  __syncthreads();

  int l = tid & 63, w = tid >> 6;
  int ln = l & 15, g4 = l >> 4;
  int lrow = w * 16 + ln;

  short8 afrag[4];
#pragma unroll
  for (int kc = 0; kc < 4; ++kc) {
    int col2 = (kc * 32 + g4 * 8) * 2;
    afrag[kc] = *(const short8*)(lds + lrow * 256 + (col2 ^ ((lrow & 7) << 4)));
  }

  f32x4 acc[24];
#pragma unroll
  for (int nt = 0; nt < 24; ++nt) acc[nt] = fzero();
#pragma unroll
  for (int nt = 0; nt < 24; ++nt) {
#pragma unroll
    for (int kc = 0; kc < 4; ++kc) {
      short8 bfrag = *(const short8*)(wqkv_bf + (size_t)(nt * 16 + ln) * 128 + kc * 32 + g4 * 8);
      acc[nt] = __builtin_amdgcn_mfma_f32_16x16x32_bf16(afrag[kc], bfrag, acc[nt], 0, 0, 0);
    }
  }

  int posb = pos0 + w * 16 + g4 * 4;
  int s_ = posb >> 5;
#pragma unroll
  for (int nt = 0; nt < 24; ++nt) {
    int o = nt * 16 + ln;
    float bias = bqkv_s[o];
    unsigned u01 = cvtpk(acc[nt][0] + bias, acc[nt][1] + bias);
    unsigned u23 = cvtpk(acc[nt][2] + bias, acc[nt][3] + bias);
    if (o < 128) {
      int bh = b * 4 + (o >> 5);
      unsigned short* p = qbuf + ((size_t)bh * L_ + posb) * 32 + (o & 31);
      p[0]  = (unsigned short)u01; p[32] = (unsigned short)(u01 >> 16);
      p[64] = (unsigned short)u23; p[96] = (unsigned short)(u23 >> 16);
    } else if (o < 256) {
      int o2 = o - 128;
      int bh = b * 4 + (o2 >> 5);
      int d = o2 & 31;
      int hi_ = (d >> 3) & 1, blk_ = d >> 4, j_ = d & 7;
      int lq0 = posb & 31;
      char* base = kf + (size_t)bh * 262144 + s_ * 2048 + blk_ * 1024 + j_ * 2
                 + (hi_ * 32 + lq0) * 16;
      *(unsigned short*)(base)      = (unsigned short)u01;
      *(unsigned short*)(base + 16) = (unsigned short)(u01 >> 16);
      *(unsigned short*)(base + 32) = (unsigned short)u23;
      *(unsigned short*)(base + 48) = (unsigned short)(u23 >> 16);
    } else {
      int ch = o - 256;
      int bh = b * 4 + (ch >> 5);
      int d = ch & 31;               // = lq (V^T row)
      int r5 = posb & 31;
      int hi_ = (r5 >> 3) & 1, blk_ = (r5 >> 4) & 1, j0 = r5 & 7;  // j0 in {0,4}
      char* addr = vf + (size_t)bh * 262144 + s_ * 2048 + blk_ * 1024
                 + (hi_ * 32 + d) * 16 + j0 * 2;
      uint2 val; val.x = u01; val.y = u23;
      *(uint2*)addr = val;
    }
  }
}

// ---------------------------------------------------------------------------
// K3: flash attention — r9 structure, with the softmax denominator moved from
// the VALU lsum-tree (2x30 ops/subtile, serial chain) to the idle MFMA pipe
// via a ones-A-fragment (mechanism correctness proven in r2-r7). The ones-
// MFMA sums over the full k=32 (both hi halves), so the epilogue shfl_xor
// disappears (the r8 bug class is structurally eliminated).
// Tripwires: WRITE_SIZE >> 4MB = spill; VGPR jump -> 3 waves/SIMD.
// ---------------------------------------------------------------------------
#define SOFTMAX_PV(SV, LACC, ACC)                                                 \
  {                                                                               \
    float p[16];                                                                  \
    _Pragma("unroll") for (int i = 0; i < 16; ++i) p[i] = fexp2((SV)[i]);         \
    unsigned u0 = cvtpk(p[0], p[1]),   u1 = cvtpk(p[2], p[3]);                    \
    unsigned u2 = cvtpk(p[4], p[5]),   u3 = cvtpk(p[6], p[7]);                    \
    unsigned u4 = cvtpk(p[8], p[9]),   u5 = cvtpk(p[10], p[11]);                  \
    unsigned u6 = cvtpk(p[12], p[13]), u7 = cvtpk(p[14], p[15]);                  \
    PLSWAP(u0, u2); PLSWAP(u1, u3); PLSWAP(u4, u6); PLSWAP(u5, u7);               \
    union { unsigned uu[4]; short8 s8; } pa, pb;                                  \
    pa.uu[0] = u0; pa.uu[1] = u1; pa.uu[2] = u2; pa.uu[3] = u3;                   \
    pb.uu[0] = u4; pb.uu[1] = u5; pb.uu[2] = u6; pb.uu[3] = u7;                   \
    ACC  = __builtin_amdgcn_mfma_f32_32x32x16_bf16(vC0, pa.s8, ACC, 0, 0, 0);     \
    ACC  = __builtin_amdgcn_mfma_f32_32x32x16_bf16(vC1, pb.s8, ACC, 0, 0, 0);     \
    LACC = __builtin_amdgcn_mfma_f32_32x32x16_bf16(ONESF, pa.s8, LACC, 0, 0, 0);  \
    LACC = __builtin_amdgcn_mfma_f32_32x32x16_bf16(ONESF, pb.s8, LACC, 0, 0, 0);  \
  }

__global__ __launch_bounds__(256, 3) void attn_g(const unsigned short* __restrict__ qbuf,
                                                 const char* __restrict__ kf,
                                                 const char* __restrict__ vf,
                                                 unsigned short* __restrict__ at) {
  __shared__ float parts[3][34][64];  // one-shot combine buffer (26112 B)
  const int bh = blockIdx.x;          // linear id %8 == bh%8 -> 2 bh per XCD L2
  const int tid = threadIdx.x;
  const int l = tid & 63, w = tid >> 6;   // w = KV quarter
  const int lq = l & 31, hi = l >> 5;
  const int lo16 = l * 16;

  const unsigned short* qb = qbuf + (size_t)bh * L_ * 32;
  const char* kp = kf + (size_t)bh * 262144 + (size_t)w * 65536 + lo16;
  const char* vp = vf + (size_t)bh * 262144 + (size_t)w * 65536 + lo16;

  const int qbase = blockIdx.y * 64;
  // Q fragments for both q-tiles (A: cols qbase+lq, B: cols qbase+32+lq)
  short8 qfA0 = *(const short8*)(qb + (size_t)(qbase + lq) * 32 + hi * 8);
  short8 qfA1 = *(const short8*)(qb + (size_t)(qbase + lq) * 32 + 16 + hi * 8);
  short8 qfB0 = *(const short8*)(qb + (size_t)(qbase + 32 + lq) * 32 + hi * 8);
  short8 qfB1 = *(const short8*)(qb + (size_t)(qbase + 32 + lq) * 32 + 16 + hi * 8);

  short8 ONESF;
#pragma unroll
  for (int i = 0; i < 8; ++i) ONESF[i] = (short)0x3F80;  // bf16 1.0
  const f32x16 ZERO = zero16();
  f32x16 accA = zero16();   // O^T[d][q] tile A (unnormalized, this KV quarter)
  f32x16 accB = zero16();   // tile B
  f32x16 laccA = zero16();  // denominator tile A (rows replicated)
  f32x16 laccB = zero16();  // denominator tile B

  // Prologue: load subtile 0
  short8 kC0 = *(const short8*)(kp);
  short8 kC1 = *(const short8*)(kp + 1024);
  short8 vC0 = *(const short8*)(vp);
  short8 vC1 = *(const short8*)(vp + 1024);

#pragma unroll 1
  for (int s = 0; s < 32; ++s) {
    // Prefetch next subtile (s=31 overreads into vf region: in-ws, unused).
    short8 kN0 = *(const short8*)(kp + 2048);
    short8 kN1 = *(const short8*)(kp + 3072);
    short8 vN0 = *(const short8*)(vp + 2048);
    short8 vN1 = *(const short8*)(vp + 3072);
    // QK^T for both q-tiles from ONE K frag pair (the KV-reuse)
    f32x16 sA = __builtin_amdgcn_mfma_f32_32x32x16_bf16(kC0, qfA0, ZERO, 0, 0, 0);
    sA = __builtin_amdgcn_mfma_f32_32x32x16_bf16(kC1, qfA1, sA, 0, 0, 0);
    f32x16 sB = __builtin_amdgcn_mfma_f32_32x32x16_bf16(kC0, qfB0, ZERO, 0, 0, 0);
    sB = __builtin_amdgcn_mfma_f32_32x32x16_bf16(kC1, qfB1, sB, 0, 0, 0);
    // softmax + PV per tile (V frag pair also reused by both)
    SOFTMAX_PV(sA, laccA, accA);
    SOFTMAX_PV(sB, laccB, accB);
    kC0 = kN0; kC1 = kN1; vC0 = vN0; vC1 = vN1;
    kp += 2048; vp += 2048;
  }

  // Intra-block KV-quarter combine through LDS (one shot).
  if (w > 0) {
    const int slot = w - 1;
#pragma unroll
    for (int r = 0; r < 16; ++r) {
      parts[slot][r][l] = accA[r];
      parts[slot][16 + r][l] = accB[r];
    }
    parts[slot][32][l] = laccA[0];
    parts[slot][33][l] = laccB[0];
  }
  __syncthreads();
  if (w == 0) {
    float lsumA = laccA[0];  // ones-MFMA summed over full k=32: no shfl needed
    float lsumB = laccB[0];
#pragma unroll
    for (int j = 0; j < 3; ++j) {
#pragma unroll
      for (int r = 0; r < 16; ++r) {
        accA[r] += parts[j][r][l];
        accB[r] += parts[j][16 + r][l];
      }
      lsumA += parts[j][32][l];
      lsumB += parts[j][33][l];
    }
    float invA = 1.f / lsumA;
    float invB = 1.f / lsumB;
    int b = bh >> 2, h = bh & 3;
    size_t baseA = ((size_t)b * L_ + qbase + lq) * 128 + h * 32;
    size_t baseB = baseA + 32 * 128;
#pragma unroll
    for (int rq = 0; rq < 4; ++rq) {
      uint2 valA, valB;
      valA.x = cvtpk(accA[rq * 4 + 0] * invA, accA[rq * 4 + 1] * invA);
      valA.y = cvtpk(accA[rq * 4 + 2] * invA, accA[rq * 4 + 3] * invA);
      valB.x = cvtpk(accB[rq * 4 + 0] * invB, accB[rq * 4 + 1] * invB);
      valB.y = cvtpk(accB[rq * 4 + 2] * invB, accB[rq * 4 + 3] * invB);
      *(uint2*)(at + baseA + rq * 8 + hi * 4) = valA;
      *(uint2*)(at + baseB + rq * 8 + hi * 4) = valB;
    }
  }
}

// ---------------------------------------------------------------------------
// K4: out = x + w_proj * a + b_proj (r9-exact, 64-pos tiles).
// ---------------------------------------------------------------------------
__global__ __launch_bounds__(256) void proj_residual(const float* __restrict__ x,
                                                     const unsigned short* __restrict__ at,
                                                     const unsigned short* __restrict__ wproj_bf,
                                                     const float* __restrict__ bproj,
                                                     float* __restrict__ out) {
  int b = blockIdx.y;
  int pos0 = blockIdx.x * 64;
  int tid = threadIdx.x;
  int l = tid & 63, w = tid >> 6;
  int ln = l & 15, g4 = l >> 4;
  int posw = pos0 + w * 16;

  short8 bfrag[4];
#pragma unroll
  for (int kc = 0; kc < 4; ++kc)
    bfrag[kc] = *(const short8*)(at + ((size_t)b * L_ + posw + ln) * 128 + kc * 32 + g4 * 8);

  f32x4 acc[8];
#pragma unroll
  for (int mt = 0; mt < 8; ++mt) acc[mt] = fzero();
#pragma unroll
  for (int mt = 0; mt < 8; ++mt) {
#pragma unroll
    for (int kc = 0; kc < 4; ++kc) {
      short8 afrag = *(const short8*)(wproj_bf + (size_t)(mt * 16 + ln) * 128 + kc * 32 + g4 * 8);
      acc[mt] = __builtin_amdgcn_mfma_f32_16x16x32_bf16(afrag, bfrag[kc], acc[mt], 0, 0, 0);
    }
  }
#pragma unroll
  for (int mt = 0; mt < 8; ++mt)
#pragma unroll
    for (int r = 0; r < 4; ++r) {
      int o = mt * 16 + g4 * 4 + r;
      int pos = posw + ln;
      size_t idx = ((size_t)b * C_ + o) * L_ + pos;
      out[idx] = x[idx] + acc[mt][r] + bproj[o];
    }
}

// ---------------------------------------------------------------------------
extern "C" void kernel_launch(void* const* d_in, const int* in_sizes, int n_in,
                              void* d_out, int out_size, void* d_ws, size_t ws_size,
                              hipStream_t stream) {
  const float* x     = (const float*)d_in[0];
  const float* gamma = (const float*)d_in[1];
  const float* beta  = (const float*)d_in[2];
  const float* wqkv  = (const float*)d_in[3];
  const float* bqkv  = (const float*)d_in[4];
  const float* wproj = (const float*)d_in[5];
  const float* bproj = (const float*)d_in[6];
  float* out = (float*)d_out;

  char* ws = (char*)d_ws;
  float* mean   = (float*)(ws + 0);
  float* rstd   = (float*)(ws + 512);
  float* bqkv_s = (float*)(ws + 1024);
  unsigned short* wqkv_bf  = (unsigned short*)(ws + 4096);
  unsigned short* wproj_bf = (unsigned short*)(ws + 102400);
  unsigned short* qbuf = (unsigned short*)(ws + 135168);
  char* kf = ws + 135168 + 4194304;          // frag-major K, 16 bh x 256KB
  char* vf = ws + 135168 + 2 * 4194304;      // frag-major V, 16 bh x 256KB
  unsigned short* at = (unsigned short*)(ws + 135168 + 3 * 4194304);

  gn_prep<<<dim3(386), 256, 0, stream>>>(x, mean, rstd, wqkv, bqkv, wproj,
                                         wqkv_bf, wproj_bf, bqkv_s);
  qkv_gemm<<<dim3(64, 4), 256, 0, stream>>>(x, gamma, beta, mean, rstd, wqkv_bf, bqkv_s,
                                            qbuf, kf, vf);
  attn_g<<<dim3(16, 64), 256, 0, stream>>>(qbuf, kf, vf, at);
  proj_residual<<<dim3(64, 4), 256, 0, stream>>>(x, at, wproj_bf, bproj, out);
}

// Round 17
// 81.180 us; speedup vs baseline: 1.0414x; 1.0414x over previous
//
#include <hip/hip_runtime.h>
#include <math.h>

// Problem constants
#define B_ 4
#define C_ 128
#define L_ 4096       // H*W
#define EPS_ 1e-5f

typedef __attribute__((ext_vector_type(8))) short short8;   // 8 x bf16 MFMA A/B frag (4 VGPRs)
typedef __attribute__((ext_vector_type(4))) float f32x4;
typedef __attribute__((ext_vector_type(16))) float f32x16;  // 32x32 MFMA C/D frag

static __device__ __forceinline__ unsigned short f2bf(float f) {
  union { float f; unsigned u; } v; v.f = f;
  return (unsigned short)((v.u + 0x7FFFu + ((v.u >> 16) & 1u)) >> 16);  // RNE
}
static __device__ __forceinline__ f32x4 fzero() {
  f32x4 z; z[0] = 0.f; z[1] = 0.f; z[2] = 0.f; z[3] = 0.f; return z;
}
static __device__ __forceinline__ f32x16 zero16() {
  f32x16 z;
#pragma unroll
  for (int i = 0; i < 16; ++i) z[i] = 0.f;
  return z;
}
static __device__ __forceinline__ float fexp2(float x) {
  return __builtin_amdgcn_exp2f(x);   // v_exp_f32
}
static __device__ __forceinline__ unsigned cvtpk(float lo, float hi) {
  unsigned r;
  asm("v_cvt_pk_bf16_f32 %0, %1, %2" : "=v"(r) : "v"(lo), "v"(hi));
  return r;
}
#define PLSWAP(a, b) asm("v_permlane32_swap_b32 %0, %1" : "+v"(a), "+v"(b))

// Frag-major K/V layout (written by qkv_gemm, read by attn_g):
//   byte addr = bh*262144 + s*2048 + blk*1024 + lane*16 + j*2
//   lane = hi*32 + lq  (lq = l&31, hi = l>>5)
//   K element: K[32s + lq][blk*16 + hi*8 + j]      (kpos-major rows)
//   V element: V^T[lq][32s + blk*16 + hi*8 + j]    (d-major rows)
// => every attention frag load is 64 lanes x 16B fully contiguous (1KB).

// ---------------------------------------------------------------------------
// K0: GroupNorm stats (blocks 0..127) + weight prep (blocks 128..385) merged.
// ---------------------------------------------------------------------------
__global__ __launch_bounds__(256) void gn_prep(const float* __restrict__ x,
                                               float* __restrict__ mean,
                                               float* __restrict__ rstd,
                                               const float* __restrict__ wqkv,
                                               const float* __restrict__ bqkv,
                                               const float* __restrict__ wproj,
                                               unsigned short* __restrict__ wqkv_bf,
                                               unsigned short* __restrict__ wproj_bf,
                                               float* __restrict__ bqkv_s) {
  int bx = blockIdx.x;
  int tid = threadIdx.x;
  if (bx < 128) {
    int g = bx & 31, b = bx >> 5;
    const f32x4* p4 = (const f32x4*)(x + (size_t)(b * C_ + g * 4) * L_);
    float s = 0.f, sq = 0.f;
#pragma unroll
    for (int i = 0; i < 16; ++i) {
      f32x4 v = p4[tid + i * 256];
      s += v[0] + v[1] + v[2] + v[3];
      sq += v[0]*v[0] + v[1]*v[1] + v[2]*v[2] + v[3]*v[3];
    }
#pragma unroll
    for (int m = 1; m < 64; m <<= 1) { s += __shfl_xor(s, m, 64); sq += __shfl_xor(sq, m, 64); }
    __shared__ float ls[8];
    int w = tid >> 6;
    if ((tid & 63) == 0) { ls[w] = s; ls[4 + w] = sq; }
    __syncthreads();
    if (tid == 0) {
      float S = ls[0] + ls[1] + ls[2] + ls[3];
      float Q = ls[4] + ls[5] + ls[6] + ls[7];
      float mu = S * (1.f / 16384.f);
      float var = Q * (1.f / 16384.f) - mu * mu;
      mean[b * 32 + g] = mu;
      rstd[b * 32 + g] = rsqrtf(var + EPS_);
    }
  } else {
    const float SC = 0.42044820762685725f * 1.2011224087864498f;  // scale*sqrt(log2e)
    int i = (bx - 128) * 256 + tid;
    if (i < 49152) {
      int o = i >> 7;
      wqkv_bf[i] = f2bf(wqkv[i] * (o < 256 ? SC : 1.f));
    } else if (i < 65536) {
      wproj_bf[i - 49152] = f2bf(wproj[i - 49152]);
    } else if (i < 65920) {
      int o = i - 65536;
      bqkv_s[o] = bqkv[o] * (o < 256 ? SC : 1.f);
    }
  }
}

// ---------------------------------------------------------------------------
// K2: fused GroupNorm-normalize + QKV 1x1 conv (r9-exact, 64-pos tiles).
// Emits q as [bh][pos][32], k/v frag-major.
// ---------------------------------------------------------------------------
__global__ __launch_bounds__(256) void qkv_gemm(const float* __restrict__ x,
                                                const float* __restrict__ gamma,
                                                const float* __restrict__ beta,
                                                const float* __restrict__ mean,
                                                const float* __restrict__ rstd,
                                                const unsigned short* __restrict__ wqkv_bf,
                                                const float* __restrict__ bqkv_s,
                                                unsigned short* __restrict__ qbuf,
                                                char* __restrict__ kf,
                                                char* __restrict__ vf) {
  __shared__ char lds[64 * 256];  // [pos][c] bf16, rows 256B, XOR-swizzled
  int b = blockIdx.y;
  int pos0 = blockIdx.x * 64;
  int tid = threadIdx.x;

#pragma unroll
  for (int it = 0; it < 4; ++it) {
    int pi = it * 256 + tid;         // 0..1023 (c-pair, 4-pos unit)
    int c = (pi >> 4) * 2;           // even c
    int pl = (pi & 15) * 4;
    const float* xc = x + (size_t)(b * C_ + c) * L_ + pos0 + pl;
    f32x4 v0 = *(const f32x4*)xc;
    f32x4 v1 = *(const f32x4*)(xc + L_);
    int g = c >> 2;                  // c,c+1 always share a group (c even)
    float rs = rstd[b * 32 + g], mu = mean[b * 32 + g];
    float A0 = rs * gamma[c],     B0 = beta[c]     - mu * A0;
    float A1 = rs * gamma[c + 1], B1 = beta[c + 1] - mu * A1;
#pragma unroll
    for (int i = 0; i < 4; ++i) {
      int row = pl + i;
      unsigned u = cvtpk(v0[i] * A0 + B0, v1[i] * A1 + B1);
      *(unsigned*)(lds + row * 256 + ((c * 2) ^ ((row & 7) << 4))) = u;
    }
  }
  __syncthreads();

  int l = tid & 63, w = tid >> 6;
  int ln = l & 15, g4 = l >> 4;
  int lrow = w * 16 + ln;

  short8 afrag[4];
#pragma unroll
  for (int kc = 0; kc < 4; ++kc) {
    int col2 = (kc * 32 + g4 * 8) * 2;
    afrag[kc] = *(const short8*)(lds + lrow * 256 + (col2 ^ ((lrow & 7) << 4)));
  }

  f32x4 acc[24];
#pragma unroll
  for (int nt = 0; nt < 24; ++nt) acc[nt] = fzero();
#pragma unroll
  for (int nt = 0; nt < 24; ++nt) {
#pragma unroll
    for (int kc = 0; kc < 4; ++kc) {
      short8 bfrag = *(const short8*)(wqkv_bf + (size_t)(nt * 16 + ln) * 128 + kc * 32 + g4 * 8);
      acc[nt] = __builtin_amdgcn_mfma_f32_16x16x32_bf16(afrag[kc], bfrag, acc[nt], 0, 0, 0);
    }
  }

  int posb = pos0 + w * 16 + g4 * 4;
  int s_ = posb >> 5;
#pragma unroll
  for (int nt = 0; nt < 24; ++nt) {
    int o = nt * 16 + ln;
    float bias = bqkv_s[o];
    unsigned u01 = cvtpk(acc[nt][0] + bias, acc[nt][1] + bias);
    unsigned u23 = cvtpk(acc[nt][2] + bias, acc[nt][3] + bias);
    if (o < 128) {
      int bh = b * 4 + (o >> 5);
      unsigned short* p = qbuf + ((size_t)bh * L_ + posb) * 32 + (o & 31);
      p[0]  = (unsigned short)u01; p[32] = (unsigned short)(u01 >> 16);
      p[64] = (unsigned short)u23; p[96] = (unsigned short)(u23 >> 16);
    } else if (o < 256) {
      int o2 = o - 128;
      int bh = b * 4 + (o2 >> 5);
      int d = o2 & 31;
      int hi_ = (d >> 3) & 1, blk_ = d >> 4, j_ = d & 7;
      int lq0 = posb & 31;
      char* base = kf + (size_t)bh * 262144 + s_ * 2048 + blk_ * 1024 + j_ * 2
                 + (hi_ * 32 + lq0) * 16;
      *(unsigned short*)(base)      = (unsigned short)u01;
      *(unsigned short*)(base + 16) = (unsigned short)(u01 >> 16);
      *(unsigned short*)(base + 32) = (unsigned short)u23;
      *(unsigned short*)(base + 48) = (unsigned short)(u23 >> 16);
    } else {
      int ch = o - 256;
      int bh = b * 4 + (ch >> 5);
      int d = ch & 31;               // = lq (V^T row)
      int r5 = posb & 31;
      int hi_ = (r5 >> 3) & 1, blk_ = (r5 >> 4) & 1, j0 = r5 & 7;  // j0 in {0,4}
      char* addr = vf + (size_t)bh * 262144 + s_ * 2048 + blk_ * 1024
                 + (hi_ * 32 + d) * 16 + j0 * 2;
      uint2 val; val.x = u01; val.y = u23;
      *(uint2*)addr = val;
    }
  }
}

// ---------------------------------------------------------------------------
// K3: flash attention — r9-exact (best measured: 50.8-51.0 us, VGPR 64,
// no spill, reproduced r13/r15). Swapped-QK^T 32x32, no-max softmax,
// global-direct frag-major loads. KV-reuse: wave = 2 q-tiles x KV quarter.
// (256,3): allocator lands at 64 arch + 64 acc = 128 -> 4 waves/SIMD.
// Full perturbation matrix (r10 unroll-2, r11 setprio, r12 hard-cap,
// r14 ping-pong, r16 MFMA-denominator) regressed or washed: this is the
// structure's register-boxed optimum.
// ---------------------------------------------------------------------------
#define SOFTMAX_PV(SV, LSUM, ACC)                                                 \
  {                                                                               \
    float p[16];                                                                  \
    _Pragma("unroll") for (int i = 0; i < 16; ++i) p[i] = fexp2((SV)[i]);         \
    LSUM += (((p[0]+p[1])+(p[2]+p[3])) + ((p[4]+p[5])+(p[6]+p[7])))               \
          + (((p[8]+p[9])+(p[10]+p[11])) + ((p[12]+p[13])+(p[14]+p[15])));        \
    unsigned u0 = cvtpk(p[0], p[1]),   u1 = cvtpk(p[2], p[3]);                    \
    unsigned u2 = cvtpk(p[4], p[5]),   u3 = cvtpk(p[6], p[7]);                    \
    unsigned u4 = cvtpk(p[8], p[9]),   u5 = cvtpk(p[10], p[11]);                  \
    unsigned u6 = cvtpk(p[12], p[13]), u7 = cvtpk(p[14], p[15]);                  \
    PLSWAP(u0, u2); PLSWAP(u1, u3); PLSWAP(u4, u6); PLSWAP(u5, u7);               \
    union { unsigned uu[4]; short8 s8; } pa, pb;                                  \
    pa.uu[0] = u0; pa.uu[1] = u1; pa.uu[2] = u2; pa.uu[3] = u3;                   \
    pb.uu[0] = u4; pb.uu[1] = u5; pb.uu[2] = u6; pb.uu[3] = u7;                   \
    ACC = __builtin_amdgcn_mfma_f32_32x32x16_bf16(vC0, pa.s8, ACC, 0, 0, 0);      \
    ACC = __builtin_amdgcn_mfma_f32_32x32x16_bf16(vC1, pb.s8, ACC, 0, 0, 0);      \
  }

__global__ __launch_bounds__(256, 3) void attn_g(const unsigned short* __restrict__ qbuf,
                                                 const char* __restrict__ kf,
                                                 const char* __restrict__ vf,
                                                 unsigned short* __restrict__ at) {
  __shared__ float parts[3][34][64];  // one-shot combine buffer (26112 B)
  const int bh = blockIdx.x;          // linear id %8 == bh%8 -> 2 bh per XCD L2
  const int tid = threadIdx.x;
  const int l = tid & 63, w = tid >> 6;   // w = KV quarter
  const int lq = l & 31, hi = l >> 5;
  const int lo16 = l * 16;

  const unsigned short* qb = qbuf + (size_t)bh * L_ * 32;
  const char* kp = kf + (size_t)bh * 262144 + (size_t)w * 65536 + lo16;
  const char* vp = vf + (size_t)bh * 262144 + (size_t)w * 65536 + lo16;

  const int qbase = blockIdx.y * 64;
  // Q fragments for both q-tiles (A: cols qbase+lq, B: cols qbase+32+lq)
  short8 qfA0 = *(const short8*)(qb + (size_t)(qbase + lq) * 32 + hi * 8);
  short8 qfA1 = *(const short8*)(qb + (size_t)(qbase + lq) * 32 + 16 + hi * 8);
  short8 qfB0 = *(const short8*)(qb + (size_t)(qbase + 32 + lq) * 32 + hi * 8);
  short8 qfB1 = *(const short8*)(qb + (size_t)(qbase + 32 + lq) * 32 + 16 + hi * 8);

  const f32x16 ZERO = zero16();
  f32x16 accA = zero16();  // O^T[d][q] tile A (unnormalized, this KV quarter)
  f32x16 accB = zero16();  // tile B
  float lsumA = 0.f, lsumB = 0.f;

  // Prologue: load subtile 0
  short8 kC0 = *(const short8*)(kp);
  short8 kC1 = *(const short8*)(kp + 1024);
  short8 vC0 = *(const short8*)(vp);
  short8 vC1 = *(const short8*)(vp + 1024);

#pragma unroll 1
  for (int s = 0; s < 32; ++s) {
    // Prefetch next subtile (s=31 overreads into vf region: in-ws, unused).
    short8 kN0 = *(const short8*)(kp + 2048);
    short8 kN1 = *(const short8*)(kp + 3072);
    short8 vN0 = *(const short8*)(vp + 2048);
    short8 vN1 = *(const short8*)(vp + 3072);
    // QK^T for both q-tiles from ONE K frag pair (the KV-reuse)
    f32x16 sA = __builtin_amdgcn_mfma_f32_32x32x16_bf16(kC0, qfA0, ZERO, 0, 0, 0);
    sA = __builtin_amdgcn_mfma_f32_32x32x16_bf16(kC1, qfA1, sA, 0, 0, 0);
    f32x16 sB = __builtin_amdgcn_mfma_f32_32x32x16_bf16(kC0, qfB0, ZERO, 0, 0, 0);
    sB = __builtin_amdgcn_mfma_f32_32x32x16_bf16(kC1, qfB1, sB, 0, 0, 0);
    // softmax + PV per tile (V frag pair also reused by both)
    SOFTMAX_PV(sA, lsumA, accA);
    SOFTMAX_PV(sB, lsumB, accB);
    kC0 = kN0; kC1 = kN1; vC0 = vN0; vC1 = vN1;
    kp += 2048; vp += 2048;
  }

  // Intra-block KV-quarter combine through LDS (one shot).
  if (w > 0) {
    const int slot = w - 1;
#pragma unroll
    for (int r = 0; r < 16; ++r) {
      parts[slot][r][l] = accA[r];
      parts[slot][16 + r][l] = accB[r];
    }
    parts[slot][32][l] = lsumA;
    parts[slot][33][l] = lsumB;
  }
  __syncthreads();
  if (w == 0) {
#pragma unroll
    for (int j = 0; j < 3; ++j) {
#pragma unroll
      for (int r = 0; r < 16; ++r) {
        accA[r] += parts[j][r][l];
        accB[r] += parts[j][16 + r][l];
      }
      lsumA += parts[j][32][l];
      lsumB += parts[j][33][l];
    }
    // Each lane's lsum covers only its hi-half (16 of 32 kpos rows):
    // exchange with lane^32 to complete the denominator.
    lsumA += __shfl_xor(lsumA, 32, 64);
    lsumB += __shfl_xor(lsumB, 32, 64);
    float invA = 1.f / lsumA;
    float invB = 1.f / lsumB;
    int b = bh >> 2, h = bh & 3;
    size_t baseA = ((size_t)b * L_ + qbase + lq) * 128 + h * 32;
    size_t baseB = baseA + 32 * 128;
#pragma unroll
    for (int rq = 0; rq < 4; ++rq) {
      uint2 valA, valB;
      valA.x = cvtpk(accA[rq * 4 + 0] * invA, accA[rq * 4 + 1] * invA);
      valA.y = cvtpk(accA[rq * 4 + 2] * invA, accA[rq * 4 + 3] * invA);
      valB.x = cvtpk(accB[rq * 4 + 0] * invB, accB[rq * 4 + 1] * invB);
      valB.y = cvtpk(accB[rq * 4 + 2] * invB, accB[rq * 4 + 3] * invB);
      *(uint2*)(at + baseA + rq * 8 + hi * 4) = valA;
      *(uint2*)(at + baseB + rq * 8 + hi * 4) = valB;
    }
  }
}

// ---------------------------------------------------------------------------
// K4: out = x + w_proj * a + b_proj (r9-exact, 64-pos tiles).
// ---------------------------------------------------------------------------
__global__ __launch_bounds__(256) void proj_residual(const float* __restrict__ x,
                                                     const unsigned short* __restrict__ at,
                                                     const unsigned short* __restrict__ wproj_bf,
                                                     const float* __restrict__ bproj,
                                                     float* __restrict__ out) {
  int b = blockIdx.y;
  int pos0 = blockIdx.x * 64;
  int tid = threadIdx.x;
  int l = tid & 63, w = tid >> 6;
  int ln = l & 15, g4 = l >> 4;
  int posw = pos0 + w * 16;

  short8 bfrag[4];
#pragma unroll
  for (int kc = 0; kc < 4; ++kc)
    bfrag[kc] = *(const short8*)(at + ((size_t)b * L_ + posw + ln) * 128 + kc * 32 + g4 * 8);

  f32x4 acc[8];
#pragma unroll
  for (int mt = 0; mt < 8; ++mt) acc[mt] = fzero();
#pragma unroll
  for (int mt = 0; mt < 8; ++mt) {
#pragma unroll
    for (int kc = 0; kc < 4; ++kc) {
      short8 afrag = *(const short8*)(wproj_bf + (size_t)(mt * 16 + ln) * 128 + kc * 32 + g4 * 8);
      acc[mt] = __builtin_amdgcn_mfma_f32_16x16x32_bf16(afrag, bfrag[kc], acc[mt], 0, 0, 0);
    }
  }
#pragma unroll
  for (int mt = 0; mt < 8; ++mt)
#pragma unroll
    for (int r = 0; r < 4; ++r) {
      int o = mt * 16 + g4 * 4 + r;
      int pos = posw + ln;
      size_t idx = ((size_t)b * C_ + o) * L_ + pos;
      out[idx] = x[idx] + acc[mt][r] + bproj[o];
    }
}

// ---------------------------------------------------------------------------
extern "C" void kernel_launch(void* const* d_in, const int* in_sizes, int n_in,
                              void* d_out, int out_size, void* d_ws, size_t ws_size,
                              hipStream_t stream) {
  const float* x     = (const float*)d_in[0];
  const float* gamma = (const float*)d_in[1];
  const float* beta  = (const float*)d_in[2];
  const float* wqkv  = (const float*)d_in[3];
  const float* bqkv  = (const float*)d_in[4];
  const float* wproj = (const float*)d_in[5];
  const float* bproj = (const float*)d_in[6];
  float* out = (float*)d_out;

  char* ws = (char*)d_ws;
  float* mean   = (float*)(ws + 0);
  float* rstd   = (float*)(ws + 512);
  float* bqkv_s = (float*)(ws + 1024);
  unsigned short* wqkv_bf  = (unsigned short*)(ws + 4096);
  unsigned short* wproj_bf = (unsigned short*)(ws + 102400);
  unsigned short* qbuf = (unsigned short*)(ws + 135168);
  char* kf = ws + 135168 + 4194304;          // frag-major K, 16 bh x 256KB
  char* vf = ws + 135168 + 2 * 4194304;      // frag-major V, 16 bh x 256KB
  unsigned short* at = (unsigned short*)(ws + 135168 + 3 * 4194304);

  gn_prep<<<dim3(386), 256, 0, stream>>>(x, mean, rstd, wqkv, bqkv, wproj,
                                         wqkv_bf, wproj_bf, bqkv_s);
  qkv_gemm<<<dim3(64, 4), 256, 0, stream>>>(x, gamma, beta, mean, rstd, wqkv_bf, bqkv_s,
                                            qbuf, kf, vf);
  attn_g<<<dim3(16, 64), 256, 0, stream>>>(qbuf, kf, vf, at);
  proj_residual<<<dim3(64, 4), 256, 0, stream>>>(x, at, wproj_bf, bproj, out);
}